// Round 8
// baseline (348.807 us; speedup 1.0000x reference)
//
#include <hip/hip_runtime.h>
#include <hip/hip_bf16.h>

#define NB 32
#define SS 1024
#define DD 768

typedef __attribute__((ext_vector_type(8))) short bf16x8;
typedef __attribute__((ext_vector_type(4))) float f32x4;

__device__ inline ushort f2bf(float f) {
    union { float f; unsigned u; } x;
    x.f = f;
    unsigned r = (x.u + 0x7fffu + ((x.u >> 16) & 1u)) >> 16;
    return (ushort)r;
}

#define GLOBAL_PTR(x) ((const __attribute__((address_space(1))) void*)(x))
#define LDS_PTR(x)    ((__attribute__((address_space(3))) void*)(x))

// ---------------------------------------------------------------- K0: f32 -> bf16 flat convert of wq and wk
__global__ void k_cvt(const float* __restrict__ wq, const float* __restrict__ wk,
                      ushort* __restrict__ wqb, ushort* __restrict__ wkb) {
    const int i = (blockIdx.x * 256 + threadIdx.x) * 4;
    const float* src = blockIdx.y ? wk : wq;
    ushort* dst = blockIdx.y ? wkb : wqb;
    const float4 v = *(const float4*)(src + i);
    ushort4 o;
    o.x = f2bf(v.x); o.y = f2bf(v.y); o.z = f2bf(v.z); o.w = f2bf(v.w);
    *(ushort4*)(dst + i) = o;
}

// ---------------------------------------------------------------- K0b: x = bf16(emb[tokens])  (32768 x 768)
__global__ void k_gather(const int* __restrict__ tokens, const float* __restrict__ emb,
                         ushort* __restrict__ xb) {
    int i = (blockIdx.x * 256 + threadIdx.x) * 4;
    int row = i / DD;
    int col = i - row * DD;
    int tok = tokens[row];
    const float4 v = *(const float4*)(emb + (size_t)tok * DD + col);
    ushort4 o;
    o.x = f2bf(v.x); o.y = f2bf(v.y); o.z = f2bf(v.z); o.w = f2bf(v.w);
    *(ushort4*)(xb + (size_t)row * DD + col) = o;
}

// ---------------------------------------------------------------- 128x128 GEMM (m97 structure, dbuf): C = A@Bt^T, bf16 out
// Used for Wt = wk@wq^T (grid 6x6) and y = x@Wt^T (grid 256x6).
__global__ __launch_bounds__(256, 2) void k_gemm_s(const ushort* __restrict__ A,
                                                   const ushort* __restrict__ Bt,
                                                   ushort* __restrict__ Cb) {
    constexpr int BK = 64;
    __shared__ ushort As[2][128 * BK];
    __shared__ ushort Bs[2][128 * BK];
    const int tid = threadIdx.x;
    const int wave = tid >> 6, lane = tid & 63;
    const int bx = blockIdx.x, by = blockIdx.y;
    const size_t abase = (size_t)bx * 128 * DD;
    const size_t bbase = (size_t)by * 128 * DD;
    const int r = tid >> 3;
    const int cc = (tid & 7) * 8;

    auto stage = [&](int buf, int k0) {
#pragma unroll
        for (int i = 0; i < 4; i++) {
            __builtin_amdgcn_global_load_lds(GLOBAL_PTR(A + abase + (size_t)(r + i * 32) * DD + k0 + cc),
                                             LDS_PTR(&As[buf][(r + i * 32) * BK + cc]), 16, 0, 0);
            __builtin_amdgcn_global_load_lds(GLOBAL_PTR(Bt + bbase + (size_t)(r + i * 32) * DD + k0 + cc),
                                             LDS_PTR(&Bs[buf][(r + i * 32) * BK + cc]), 16, 0, 0);
        }
    };

    f32x4 acc[4][4] = {};
    const int wm = (wave >> 1) * 64, wn = (wave & 1) * 64;
    const int lr = lane & 15, lc = (lane >> 4) * 8;

    stage(0, 0);
    __syncthreads();
    int cur = 0;
#pragma unroll 1
    for (int k0 = 0; k0 < DD; k0 += BK) {
        if (k0 + BK < DD) stage(cur ^ 1, k0 + BK);
        const ushort* as = As[cur];
        const ushort* bs = Bs[cur];
#pragma unroll
        for (int kk = 0; kk < 2; kk++) {
            bf16x8 af[4], bfv[4];
#pragma unroll
            for (int m = 0; m < 4; m++)
                af[m] = *(const bf16x8*)(as + (wm + m * 16 + lr) * BK + kk * 32 + lc);
#pragma unroll
            for (int n = 0; n < 4; n++)
                bfv[n] = *(const bf16x8*)(bs + (wn + n * 16 + lr) * BK + kk * 32 + lc);
#pragma unroll
            for (int m = 0; m < 4; m++)
#pragma unroll
                for (int n = 0; n < 4; n++)
                    acc[m][n] = __builtin_amdgcn_mfma_f32_16x16x32_bf16(af[m], bfv[n], acc[m][n], 0, 0, 0);
        }
        __syncthreads();
        cur ^= 1;
    }
    const int rowbase = bx * 128 + wm + (lane >> 4) * 4;
    const int colbase = by * 128 + wn + (lane & 15);
#pragma unroll
    for (int m = 0; m < 4; m++)
#pragma unroll
        for (int n = 0; n < 4; n++)
#pragma unroll
            for (int j = 0; j < 4; j++)
                Cb[(size_t)(rowbase + m * 16 + j) * DD + colbase + n * 16] = f2bf(acc[m][n][j]);
}

// ---------------------------------------------------------------- fused QK^T + masked softmax, 2-phase BK=32 dbuf
// block = 64 rows x full 1024 cols; both operands LDS-staged per 32-wide K-slice,
// prefetch(t+1) issued BEFORE compute(t) (R4-proven 2ph pattern).
// grid 512 (epochs of 128; batch = g*8 + w%8, rowblock = w/8), 512 thr.
__global__ __launch_bounds__(512) void k_attn(const ushort* __restrict__ Y,
                                              const ushort* __restrict__ X,
                                              const int* __restrict__ mask,
                                              float* __restrict__ Aout) {
    __shared__ ushort Bsh[2][SS * 32];  // 2 x 64 KB, swizzled rows (64 B)
    __shared__ ushort Ash[2][64 * 32];  // 2 x 4 KB
    __shared__ int    Msk[SS];          // 4 KB
    __shared__ float  RedM[8][64];      // 2 KB
    __shared__ float  RedS[8][64];      // 2 KB

    const int tid = threadIdx.x;
    const int wid = tid >> 6, lane = tid & 63;
    const int la = lane & 15, lg = lane >> 4;

    const int wgid = blockIdx.x;
    const int g = wgid >> 7, w = wgid & 127;
    const int b = g * 8 + (w & 7);
    const int bx = w >> 3;                       // row-block 0..15
    const ushort* Ag = Y + (size_t)b * SS * DD + (size_t)bx * 64 * DD;
    const ushort* Bg = X + (size_t)b * SS * DD;
    float* Ao = Aout + (size_t)b * SS * SS + (size_t)bx * 64 * SS;

    Msk[tid] = mask[b * SS + tid];
    Msk[tid + 512] = mask[b * SS + tid + 512];

    // staging: linear LDS dest + pre-swizzled global source (rule #21).
    // row = 64 B; swizzle: byte-col cb ^= ((row&3)<<4).
    auto stageB = [&](ushort* dst, const ushort* gsrc) {   // gsrc = Bg + k0; 64 KB slice
#pragma unroll
        for (int l = 0; l < 8; l++) {
            const int L = (l * 512 + tid) * 16;            // linear byte offset
            const int r = L >> 6;                          // row 0..1023
            const int scol = ((L & 63) ^ ((r & 3) << 4)) >> 1;
            __builtin_amdgcn_global_load_lds(GLOBAL_PTR(gsrc + (size_t)r * DD + scol),
                                             LDS_PTR(dst + (L >> 1)), 16, 0, 0);
        }
    };
    auto stageA = [&](ushort* dst, const ushort* gsrc) {   // 4 KB slice, waves 0-3 only
        if (tid < 256) {
            const int L = tid * 16;
            const int r = L >> 6;                          // row 0..63
            const int scol = ((L & 63) ^ ((r & 3) << 4)) >> 1;
            __builtin_amdgcn_global_load_lds(GLOBAL_PTR(gsrc + (size_t)r * DD + scol),
                                             LDS_PTR(dst + (L >> 1)), 16, 0, 0);
        }
    };

    // read-side: fragment row rr (rr&3 == la&3), k-group lg -> same XOR
    const int koff = ((lg ^ (la & 3)) << 3);               // ushort offset within 32-ush row

    f32x4 acc[4][8] = {};

    stageA(&Ash[0][0], Ag);
    stageB(&Bsh[0][0], Bg);
    __syncthreads();   // Msk + slice 0 ready (vmcnt(0) drain)

#pragma unroll 1
    for (int t = 0; t < 24; t++) {
        if (t < 23) {
            const int k1 = (t + 1) * 32;
            stageA(&Ash[(t + 1) & 1][0], Ag + k1);
            stageB(&Bsh[(t + 1) & 1][0], Bg + k1);
        }
        const ushort* ash = &Ash[t & 1][0];
        const ushort* bsh = &Bsh[t & 1][0];
        bf16x8 af[4];
#pragma unroll
        for (int m = 0; m < 4; m++)
            af[m] = *(const bf16x8*)(ash + (m * 16 + la) * 32 + koff);
#pragma unroll
        for (int n = 0; n < 8; n++) {
            const bf16x8 bf = *(const bf16x8*)(bsh + (wid * 128 + n * 16 + la) * 32 + koff);
            __builtin_amdgcn_s_setprio(1);
#pragma unroll
            for (int m = 0; m < 4; m++)
                acc[m][n] = __builtin_amdgcn_mfma_f32_16x16x32_bf16(af[m], bf, acc[m][n], 0, 0, 0);
            __builtin_amdgcn_s_setprio(0);
        }
        __syncthreads();   // drains prefetch; protects dbuf swap
    }

    // ---- in-block masked softmax over full rows ----
    float bias[8];
#pragma unroll
    for (int n = 0; n < 8; n++)
        bias[n] = Msk[wid * 128 + n * 16 + la] ? -1e9f : 0.0f;

    float mxl[4][4];
#pragma unroll
    for (int m = 0; m < 4; m++)
#pragma unroll
        for (int j = 0; j < 4; j++) {
            float v = -3.4e38f;
#pragma unroll
            for (int n = 0; n < 8; n++) v = fmaxf(v, acc[m][n][j] + bias[n]);
#pragma unroll
            for (int off = 1; off < 16; off <<= 1) v = fmaxf(v, __shfl_xor(v, off));
            mxl[m][j] = v;
        }
    if (la == 0) {
#pragma unroll
        for (int m = 0; m < 4; m++)
#pragma unroll
            for (int j = 0; j < 4; j++)
                RedM[wid][m * 16 + lg * 4 + j] = mxl[m][j];
    }
    __syncthreads();
#pragma unroll
    for (int m = 0; m < 4; m++)
#pragma unroll
        for (int j = 0; j < 4; j++) {
            const int r = m * 16 + lg * 4 + j;
            float v = RedM[0][r];
#pragma unroll
            for (int ww = 1; ww < 8; ww++) v = fmaxf(v, RedM[ww][r]);
            mxl[m][j] = v;
        }

    float sml[4][4];
#pragma unroll
    for (int m = 0; m < 4; m++)
#pragma unroll
        for (int j = 0; j < 4; j++) {
            float s = 0.f;
#pragma unroll
            for (int n = 0; n < 8; n++) {
                const float e = __expf(acc[m][n][j] + bias[n] - mxl[m][j]);
                acc[m][n][j] = e;
                s += e;
            }
#pragma unroll
            for (int off = 1; off < 16; off <<= 1) s += __shfl_xor(s, off);
            sml[m][j] = s;
        }
    if (la == 0) {
#pragma unroll
        for (int m = 0; m < 4; m++)
#pragma unroll
            for (int j = 0; j < 4; j++)
                RedS[wid][m * 16 + lg * 4 + j] = sml[m][j];
    }
    __syncthreads();
#pragma unroll
    for (int m = 0; m < 4; m++)
#pragma unroll
        for (int j = 0; j < 4; j++) {
            const int r = m * 16 + lg * 4 + j;
            float s = RedS[0][r];
#pragma unroll
            for (int ww = 1; ww < 8; ww++) s += RedS[ww][r];
            const float inv = 1.0f / s;
#pragma unroll
            for (int n = 0; n < 8; n++)
                Ao[(size_t)r * SS + wid * 128 + n * 16 + la] = acc[m][n][j] * inv;
        }
}

// ---------------------------------------------------------------- K4a: partial xbar[b][k] = sum_t a[b,0,t]*emb[tok[b,t]][k]
__global__ __launch_bounds__(256) void k_xbar(const float* __restrict__ a, const int* __restrict__ tokens,
                                              const float* __restrict__ emb, float* __restrict__ part) {
    const int b = blockIdx.x >> 3, c = blockIdx.x & 7;
    __shared__ float a0s[128];
    __shared__ int toks[128];
    const int tid = threadIdx.x;
    if (tid < 128) {
        a0s[tid] = a[(size_t)b * SS * SS + c * 128 + tid];
        toks[tid] = tokens[b * SS + c * 128 + tid];
    }
    __syncthreads();
    float acc0 = 0.f, acc1 = 0.f, acc2 = 0.f;
#pragma unroll 4
    for (int t = 0; t < 128; t++) {
        const float at = a0s[t];
        const float* er = emb + (size_t)toks[t] * DD;
        acc0 = fmaf(at, er[tid], acc0);
        acc1 = fmaf(at, er[tid + 256], acc1);
        acc2 = fmaf(at, er[tid + 512], acc2);
    }
    float* p = part + ((size_t)c * NB + b) * DD;
    p[tid] = acc0; p[tid + 256] = acc1; p[tid + 512] = acc2;
}

// ---------------------------------------------------------------- K5: cls[b][c] = sum_k xbar[b][k] * wv[k][c]
__global__ __launch_bounds__(128) void k_cls(const float* __restrict__ part, const float* __restrict__ wv,
                                             float* __restrict__ cls) {
    const int b = blockIdx.y, tid = threadIdx.x;
    const int c = blockIdx.x * 128 + tid;
    __shared__ float xb[DD];
#pragma unroll
    for (int j = 0; j < 6; j++) {
        const int k = tid + j * 128;
        float s = 0.f;
#pragma unroll
        for (int p = 0; p < 8; p++) s += part[((size_t)p * NB + b) * DD + k];
        xb[k] = s;
    }
    __syncthreads();
    float acc = 0.f;
#pragma unroll 8
    for (int k = 0; k < DD; k++) acc = fmaf(xb[k], wv[(size_t)k * DD + c], acc);
    cls[(size_t)b * DD + c] = acc;
}

__device__ inline float block_sum256(float v, float* red, int tid) {
#pragma unroll
    for (int off = 32; off; off >>= 1) v += __shfl_xor(v, off);
    __syncthreads();
    if ((tid & 63) == 0) red[tid >> 6] = v;
    __syncthreads();
    return red[0] + red[1] + red[2] + red[3];
}

// ---------------------------------------------------------------- K6: LayerNorm per batch
__global__ __launch_bounds__(256) void k_ln(const float* __restrict__ cls, const float* __restrict__ ln_g,
                                            const float* __restrict__ ln_b, float* __restrict__ hs) {
    const int b = blockIdx.x, tid = threadIdx.x;
    __shared__ float red[4];
    float v[3];
#pragma unroll
    for (int j = 0; j < 3; j++) v[j] = cls[(size_t)b * DD + tid + j * 256];
    const float mu = block_sum256(v[0] + v[1] + v[2], red, tid) * (1.0f / DD);
    float dv = 0.f;
#pragma unroll
    for (int j = 0; j < 3; j++) { const float d = v[j] - mu; dv += d * d; }
    __syncthreads();
    const float var = block_sum256(dv, red, tid) * (1.0f / DD);
    const float sc = 1.0f / sqrtf(var + 1e-5f);
#pragma unroll
    for (int j = 0; j < 3; j++) {
        const int d = tid + j * 256;
        hs[(size_t)b * DD + d] = (v[j] - mu) * sc * ln_g[d] + ln_b[d];
    }
}

// ---------------------------------------------------------------- K7: g = gelu(hs@w1+b1); partial logits per 128-col chunk
__global__ __launch_bounds__(128) void k_mlp(const float* __restrict__ hs, const float* __restrict__ w1,
                                             const float* __restrict__ b1, const float* __restrict__ wh,
                                             float* __restrict__ part_l) {
    const int b = blockIdx.y, tid = threadIdx.x;
    const int j = blockIdx.x * 128 + tid;
    __shared__ float h[DD];
#pragma unroll
    for (int q = 0; q < 6; q++) h[tid + q * 128] = hs[(size_t)b * DD + tid + q * 128];
    __syncthreads();
    float p = b1[j];
#pragma unroll 8
    for (int d = 0; d < DD; d++) p = fmaf(h[d], w1[(size_t)d * DD + j], p);
    const float g = 0.5f * p * (1.0f + erff(p * 0.70710678118654752f));
    float l0 = g * wh[j * 2 + 0];
    float l1 = g * wh[j * 2 + 1];
#pragma unroll
    for (int off = 32; off; off >>= 1) { l0 += __shfl_xor(l0, off); l1 += __shfl_xor(l1, off); }
    __shared__ float r0[2], r1[2];
    if ((tid & 63) == 0) { r0[tid >> 6] = l0; r1[tid >> 6] = l1; }
    __syncthreads();
    if (tid == 0) {
        part_l[((size_t)b * 6 + blockIdx.x) * 2 + 0] = r0[0] + r0[1];
        part_l[((size_t)b * 6 + blockIdx.x) * 2 + 1] = r1[0] + r1[1];
    }
}

// ---------------------------------------------------------------- K8: final logits reduce
__global__ __launch_bounds__(64) void k_final(const float* __restrict__ part_l, const float* __restrict__ bh,
                                              float* __restrict__ out) {
    const int b = threadIdx.x;
    if (b < NB) {
        float l0 = bh[0], l1 = bh[1];
#pragma unroll
        for (int c = 0; c < 6; c++) {
            l0 += part_l[((size_t)b * 6 + c) * 2 + 0];
            l1 += part_l[((size_t)b * 6 + c) * 2 + 1];
        }
        out[b * 2 + 0] = l0;
        out[b * 2 + 1] = l1;
    }
}

// ----------------------------------------------------------------
extern "C" void kernel_launch(void* const* d_in, const int* in_sizes, int n_in,
                              void* d_out, int out_size, void* d_ws, size_t ws_size,
                              hipStream_t stream) {
    const int*   tokens = (const int*)d_in[0];
    const int*   mask   = (const int*)d_in[1];
    const float* emb    = (const float*)d_in[2];
    const float* wq     = (const float*)d_in[3];
    const float* wk     = (const float*)d_in[4];
    const float* wv     = (const float*)d_in[5];
    const float* ln_g   = (const float*)d_in[6];
    const float* ln_b   = (const float*)d_in[7];
    const float* w1     = (const float*)d_in[8];
    const float* b1     = (const float*)d_in[9];
    const float* wh     = (const float*)d_in[10];
    const float* bh     = (const float*)d_in[11];
    float* out = (float*)d_out;

    char* ws = (char*)d_ws;
    const size_t XB = (size_t)NB * SS * DD * 2;   // 50,331,648 B
    const size_t WB = (size_t)DD * DD * 2;        // 1,179,648 B
    ushort* xb  = (ushort*)ws;                    // x bf16
    ushort* yb  = (ushort*)(ws + XB);             // y = x @ W bf16
    ushort* wqb = (ushort*)(ws + 2 * XB);         // wq bf16
    ushort* wkb = (ushort*)(ws + 2 * XB + WB);    // wk bf16
    ushort* Wt  = (ushort*)(ws + 2 * XB + 2 * WB);// Wt[e][d] = (wq wk^T)[d][e] bf16
    char*   p4  = ws + 2 * XB + 3 * WB;
    float*  part   = (float*)p4;                          // 8*32*768*4
    float*  cls    = (float*)(p4 + 786432);               // 32*768*4
    float*  hsb    = (float*)(p4 + 786432 + 98304);       // 32*768*4
    float*  part_l = (float*)(p4 + 786432 + 2 * 98304);   // 32*6*2*4

    float* a_region = out + 64;  // a: B*S*S floats

    k_cvt<<<dim3(576, 2), 256, 0, stream>>>(wq, wk, wqb, wkb);
    k_gather<<<24576, 256, 0, stream>>>(tokens, emb, xb);
    // Wt = wk @ wq^T  (Wt[e][d] = sum_j wk[e,j] wq[d,j] = W[d,e])
    k_gemm_s<<<dim3(6, 6), 256, 0, stream>>>(wkb, wqb, Wt);
    // y = x @ W  (y[s,e] = sum_d x[s,d] Wt[e,d]) -- balanced 1536-block grid, 2 blocks/CU
    k_gemm_s<<<dim3(256, 6), 256, 0, stream>>>(xb, Wt, yb);
    // a = softmax(y @ x^T + mask), fused, 2-phase BK=32
    k_attn<<<512, 512, 0, stream>>>(yb, xb, mask, a_region);
    k_xbar<<<256, 256, 0, stream>>>(a_region, tokens, emb, part);
    k_cls<<<dim3(6, NB), 128, 0, stream>>>(part, wv, cls);
    k_ln<<<NB, 256, 0, stream>>>(cls, ln_g, ln_b, hsb);
    k_mlp<<<dim3(6, NB), 128, 0, stream>>>(hsb, w1, b1, wh, part_l);
    k_final<<<1, 64, 0, stream>>>(part_l, bh, out);
}

// Round 9
// 344.002 us; speedup vs baseline: 1.0140x; 1.0140x over previous
//
#include <hip/hip_runtime.h>
#include <hip/hip_bf16.h>

#define NB 32
#define SS 1024
#define DD 768

typedef __attribute__((ext_vector_type(8))) short bf16x8;
typedef __attribute__((ext_vector_type(4))) float f32x4;

__device__ inline ushort f2bf(float f) {
    union { float f; unsigned u; } x;
    x.f = f;
    unsigned r = (x.u + 0x7fffu + ((x.u >> 16) & 1u)) >> 16;
    return (ushort)r;
}

#define GLOBAL_PTR(x) ((const __attribute__((address_space(1))) void*)(x))
#define LDS_PTR(x)    ((__attribute__((address_space(3))) void*)(x))

// ---------------------------------------------------------------- K0: f32 -> bf16 flat convert of wq and wk
__global__ void k_cvt(const float* __restrict__ wq, const float* __restrict__ wk,
                      ushort* __restrict__ wqb, ushort* __restrict__ wkb) {
    const int i = (blockIdx.x * 256 + threadIdx.x) * 4;
    const float* src = blockIdx.y ? wk : wq;
    ushort* dst = blockIdx.y ? wkb : wqb;
    const float4 v = *(const float4*)(src + i);
    ushort4 o;
    o.x = f2bf(v.x); o.y = f2bf(v.y); o.z = f2bf(v.z); o.w = f2bf(v.w);
    *(ushort4*)(dst + i) = o;
}

// ---------------------------------------------------------------- K0b: x = bf16(emb[tokens])  (32768 x 768)
__global__ void k_gather(const int* __restrict__ tokens, const float* __restrict__ emb,
                         ushort* __restrict__ xb) {
    int i = (blockIdx.x * 256 + threadIdx.x) * 4;
    int row = i / DD;
    int col = i - row * DD;
    int tok = tokens[row];
    const float4 v = *(const float4*)(emb + (size_t)tok * DD + col);
    ushort4 o;
    o.x = f2bf(v.x); o.y = f2bf(v.y); o.z = f2bf(v.z); o.w = f2bf(v.w);
    *(ushort4*)(xb + (size_t)row * DD + col) = o;
}

// ---------------------------------------------------------------- 128x128 GEMM (m97 structure, dbuf): C = A@Bt^T, bf16 out
__global__ __launch_bounds__(256, 2) void k_gemm_s(const ushort* __restrict__ A,
                                                   const ushort* __restrict__ Bt,
                                                   ushort* __restrict__ Cb) {
    constexpr int BK = 64;
    __shared__ ushort As[2][128 * BK];
    __shared__ ushort Bs[2][128 * BK];
    const int tid = threadIdx.x;
    const int wave = tid >> 6, lane = tid & 63;
    const int bx = blockIdx.x, by = blockIdx.y;
    const size_t abase = (size_t)bx * 128 * DD;
    const size_t bbase = (size_t)by * 128 * DD;
    const int r = tid >> 3;
    const int cc = (tid & 7) * 8;

    auto stage = [&](int buf, int k0) {
#pragma unroll
        for (int i = 0; i < 4; i++) {
            __builtin_amdgcn_global_load_lds(GLOBAL_PTR(A + abase + (size_t)(r + i * 32) * DD + k0 + cc),
                                             LDS_PTR(&As[buf][(r + i * 32) * BK + cc]), 16, 0, 0);
            __builtin_amdgcn_global_load_lds(GLOBAL_PTR(Bt + bbase + (size_t)(r + i * 32) * DD + k0 + cc),
                                             LDS_PTR(&Bs[buf][(r + i * 32) * BK + cc]), 16, 0, 0);
        }
    };

    f32x4 acc[4][4] = {};
    const int wm = (wave >> 1) * 64, wn = (wave & 1) * 64;
    const int lr = lane & 15, lc = (lane >> 4) * 8;

    stage(0, 0);
    __syncthreads();
    int cur = 0;
#pragma unroll 1
    for (int k0 = 0; k0 < DD; k0 += BK) {
        if (k0 + BK < DD) stage(cur ^ 1, k0 + BK);
        const ushort* as = As[cur];
        const ushort* bs = Bs[cur];
#pragma unroll
        for (int kk = 0; kk < 2; kk++) {
            bf16x8 af[4], bfv[4];
#pragma unroll
            for (int m = 0; m < 4; m++)
                af[m] = *(const bf16x8*)(as + (wm + m * 16 + lr) * BK + kk * 32 + lc);
#pragma unroll
            for (int n = 0; n < 4; n++)
                bfv[n] = *(const bf16x8*)(bs + (wn + n * 16 + lr) * BK + kk * 32 + lc);
#pragma unroll
            for (int m = 0; m < 4; m++)
#pragma unroll
                for (int n = 0; n < 4; n++)
                    acc[m][n] = __builtin_amdgcn_mfma_f32_16x16x32_bf16(af[m], bfv[n], acc[m][n], 0, 0, 0);
        }
        __syncthreads();
        cur ^= 1;
    }
    const int rowbase = bx * 128 + wm + (lane >> 4) * 4;
    const int colbase = by * 128 + wn + (lane & 15);
#pragma unroll
    for (int m = 0; m < 4; m++)
#pragma unroll
        for (int n = 0; n < 4; n++)
#pragma unroll
            for (int j = 0; j < 4; j++)
                Cb[(size_t)(rowbase + m * 16 + j) * DD + colbase + n * 16] = f2bf(acc[m][n][j]);
}

// ---------------------------------------------------------------- fused QK^T + masked softmax, wave-private dbuf staging
// block = 64 rows x 1024 cols; wave wid owns cols [wid*128, +128) -> stages ONLY
// its own B rows into private LDS dbuf; A-frags in regs (dbuf). NO barriers in
// the K-loop: per-wave s_waitcnt vmcnt(0) orders stage->read (all wave-local).
// grid 512 (epochs of 128; batch = g*8 + w%8, rowblock = w/8), 512 thr.
__global__ __launch_bounds__(512) void k_attn(const ushort* __restrict__ Y,
                                              const ushort* __restrict__ X,
                                              const int* __restrict__ mask,
                                              float* __restrict__ Aout) {
    __shared__ ushort Bsh[8][2][128 * 32];  // per-wave dbuf: 8 x 2 x 8 KB = 128 KB
    __shared__ int    Msk[SS];              // 4 KB
    __shared__ float  RedM[8][64];          // 2 KB
    __shared__ float  RedS[8][64];          // 2 KB

    const int tid = threadIdx.x;
    const int wid = tid >> 6, lane = tid & 63;
    const int la = lane & 15, lg = lane >> 4;

    const int wgid = blockIdx.x;
    const int g = wgid >> 7, w = wgid & 127;
    const int b = g * 8 + (w & 7);
    const int bx = w >> 3;                       // row-block 0..15
    const ushort* Ag = Y + (size_t)b * SS * DD + (size_t)bx * 64 * DD;
    const ushort* Bg = X + (size_t)b * SS * DD + (size_t)wid * 128 * DD;  // wave's col-rows
    float* Ao = Aout + (size_t)b * SS * SS + (size_t)bx * 64 * SS;

    Msk[tid] = mask[b * SS + tid];
    Msk[tid + 512] = mask[b * SS + tid + 512];

    // B staging (per wave): 8 insts x 1KB cover 128 rows x 64B. Lane l of inst i:
    // local row r = i*16 + (l>>2), 16B chunk c = l&3; dest linear = base + i*1KB + l*16B;
    // source col chunk = c ^ (r&3)  (pre-swizzled source, linear dest — rule #21).
    const int sr = lane >> 2;                           // row within 16-row group
    const int scc = ((lane & 3) ^ (sr & 3)) << 3;       // swizzled src col (ushorts)
    // read-side: global k-chunk lg of row rr lives at LDS chunk lg^(rr&3), rr&3==la&3
    const int koff = (lg ^ (la & 3)) << 3;

    ushort* wb0 = &Bsh[wid][0][0];
    ushort* wb1 = &Bsh[wid][1][0];

    auto stageB = [&](ushort* dst, int k0) {
#pragma unroll
        for (int i = 0; i < 8; i++)
            __builtin_amdgcn_global_load_lds(GLOBAL_PTR(Bg + (size_t)(i * 16 + sr) * DD + k0 + scc),
                                             LDS_PTR(dst + i * 512), 16, 0, 0);
    };
    auto loadA = [&](bf16x8* af, int k0) {
#pragma unroll
        for (int m = 0; m < 4; m++)
            af[m] = *(const bf16x8*)(Ag + (size_t)(m * 16 + la) * DD + k0 + lg * 8);
    };

    f32x4 acc[4][8] = {};
    bf16x8 afA[4], afB[4];

    auto comp = [&](const ushort* bsh, const bf16x8* af) {
#pragma unroll
        for (int n = 0; n < 8; n++) {
            const bf16x8 bf = *(const bf16x8*)(bsh + (n * 16 + la) * 32 + koff);
            __builtin_amdgcn_s_setprio(1);
#pragma unroll
            for (int m = 0; m < 4; m++)
                acc[m][n] = __builtin_amdgcn_mfma_f32_16x16x32_bf16(af[m], bf, acc[m][n], 0, 0, 0);
            __builtin_amdgcn_s_setprio(0);
        }
    };

    // prologue: slice 0 into buf0/afA (wave-local wait, no barrier)
    stageB(wb0, 0);
    loadA(afA, 0);
    asm volatile("s_waitcnt vmcnt(0)" ::: "memory");
    __builtin_amdgcn_sched_barrier(0);

#pragma unroll 1
    for (int tt = 0; tt < 12; tt++) {
        const int t0 = tt * 2;
        // half-step A: compute buf0/afA(t0); prefetch buf1/afB(t0+1)
        if (t0 + 1 < 24) { stageB(wb1, (t0 + 1) * 32); loadA(afB, (t0 + 1) * 32); }
        comp(wb0, afA);
        asm volatile("s_waitcnt vmcnt(0)" ::: "memory");
        __builtin_amdgcn_sched_barrier(0);
        // half-step B: compute buf1/afB(t0+1); prefetch buf0/afA(t0+2)
        if (t0 + 2 < 24) { stageB(wb0, (t0 + 2) * 32); loadA(afA, (t0 + 2) * 32); }
        comp(wb1, afB);
        asm volatile("s_waitcnt vmcnt(0)" ::: "memory");
        __builtin_amdgcn_sched_barrier(0);
    }
    __syncthreads();   // all waves done; Msk visible; Red* safe

    // ---- in-block masked softmax over full rows (unchanged, proven) ----
    float bias[8];
#pragma unroll
    for (int n = 0; n < 8; n++)
        bias[n] = Msk[wid * 128 + n * 16 + la] ? -1e9f : 0.0f;

    float mxl[4][4];
#pragma unroll
    for (int m = 0; m < 4; m++)
#pragma unroll
        for (int j = 0; j < 4; j++) {
            float v = -3.4e38f;
#pragma unroll
            for (int n = 0; n < 8; n++) v = fmaxf(v, acc[m][n][j] + bias[n]);
#pragma unroll
            for (int off = 1; off < 16; off <<= 1) v = fmaxf(v, __shfl_xor(v, off));
            mxl[m][j] = v;
        }
    if (la == 0) {
#pragma unroll
        for (int m = 0; m < 4; m++)
#pragma unroll
            for (int j = 0; j < 4; j++)
                RedM[wid][m * 16 + lg * 4 + j] = mxl[m][j];
    }
    __syncthreads();
#pragma unroll
    for (int m = 0; m < 4; m++)
#pragma unroll
        for (int j = 0; j < 4; j++) {
            const int r = m * 16 + lg * 4 + j;
            float v = RedM[0][r];
#pragma unroll
            for (int ww = 1; ww < 8; ww++) v = fmaxf(v, RedM[ww][r]);
            mxl[m][j] = v;
        }

    float sml[4][4];
#pragma unroll
    for (int m = 0; m < 4; m++)
#pragma unroll
        for (int j = 0; j < 4; j++) {
            float s = 0.f;
#pragma unroll
            for (int n = 0; n < 8; n++) {
                const float e = __expf(acc[m][n][j] + bias[n] - mxl[m][j]);
                acc[m][n][j] = e;
                s += e;
            }
#pragma unroll
            for (int off = 1; off < 16; off <<= 1) s += __shfl_xor(s, off);
            sml[m][j] = s;
        }
    if (la == 0) {
#pragma unroll
        for (int m = 0; m < 4; m++)
#pragma unroll
            for (int j = 0; j < 4; j++)
                RedS[wid][m * 16 + lg * 4 + j] = sml[m][j];
    }
    __syncthreads();
#pragma unroll
    for (int m = 0; m < 4; m++)
#pragma unroll
        for (int j = 0; j < 4; j++) {
            const int r = m * 16 + lg * 4 + j;
            float s = RedS[0][r];
#pragma unroll
            for (int ww = 1; ww < 8; ww++) s += RedS[ww][r];
            const float inv = 1.0f / s;
#pragma unroll
            for (int n = 0; n < 8; n++)
                Ao[(size_t)r * SS + wid * 128 + n * 16 + la] = acc[m][n][j] * inv;
        }
}

// ---------------------------------------------------------------- K4a: partial xbar[b][k] = sum_t a[b,0,t]*emb[tok[b,t]][k]
__global__ __launch_bounds__(256) void k_xbar(const float* __restrict__ a, const int* __restrict__ tokens,
                                              const float* __restrict__ emb, float* __restrict__ part) {
    const int b = blockIdx.x >> 3, c = blockIdx.x & 7;
    __shared__ float a0s[128];
    __shared__ int toks[128];
    const int tid = threadIdx.x;
    if (tid < 128) {
        a0s[tid] = a[(size_t)b * SS * SS + c * 128 + tid];
        toks[tid] = tokens[b * SS + c * 128 + tid];
    }
    __syncthreads();
    float acc0 = 0.f, acc1 = 0.f, acc2 = 0.f;
#pragma unroll 4
    for (int t = 0; t < 128; t++) {
        const float at = a0s[t];
        const float* er = emb + (size_t)toks[t] * DD;
        acc0 = fmaf(at, er[tid], acc0);
        acc1 = fmaf(at, er[tid + 256], acc1);
        acc2 = fmaf(at, er[tid + 512], acc2);
    }
    float* p = part + ((size_t)c * NB + b) * DD;
    p[tid] = acc0; p[tid + 256] = acc1; p[tid + 512] = acc2;
}

// ---------------------------------------------------------------- K5: cls[b][c] = sum_k xbar[b][k] * wv[k][c]
__global__ __launch_bounds__(128) void k_cls(const float* __restrict__ part, const float* __restrict__ wv,
                                             float* __restrict__ cls) {
    const int b = blockIdx.y, tid = threadIdx.x;
    const int c = blockIdx.x * 128 + tid;
    __shared__ float xb[DD];
#pragma unroll
    for (int j = 0; j < 6; j++) {
        const int k = tid + j * 128;
        float s = 0.f;
#pragma unroll
        for (int p = 0; p < 8; p++) s += part[((size_t)p * NB + b) * DD + k];
        xb[k] = s;
    }
    __syncthreads();
    float acc = 0.f;
#pragma unroll 8
    for (int k = 0; k < DD; k++) acc = fmaf(xb[k], wv[(size_t)k * DD + c], acc);
    cls[(size_t)b * DD + c] = acc;
}

__device__ inline float block_sum256(float v, float* red, int tid) {
#pragma unroll
    for (int off = 32; off; off >>= 1) v += __shfl_xor(v, off);
    __syncthreads();
    if ((tid & 63) == 0) red[tid >> 6] = v;
    __syncthreads();
    return red[0] + red[1] + red[2] + red[3];
}

// ---------------------------------------------------------------- K6: LayerNorm per batch
__global__ __launch_bounds__(256) void k_ln(const float* __restrict__ cls, const float* __restrict__ ln_g,
                                            const float* __restrict__ ln_b, float* __restrict__ hs) {
    const int b = blockIdx.x, tid = threadIdx.x;
    __shared__ float red[4];
    float v[3];
#pragma unroll
    for (int j = 0; j < 3; j++) v[j] = cls[(size_t)b * DD + tid + j * 256];
    const float mu = block_sum256(v[0] + v[1] + v[2], red, tid) * (1.0f / DD);
    float dv = 0.f;
#pragma unroll
    for (int j = 0; j < 3; j++) { const float d = v[j] - mu; dv += d * d; }
    __syncthreads();
    const float var = block_sum256(dv, red, tid) * (1.0f / DD);
    const float sc = 1.0f / sqrtf(var + 1e-5f);
#pragma unroll
    for (int j = 0; j < 3; j++) {
        const int d = tid + j * 256;
        hs[(size_t)b * DD + d] = (v[j] - mu) * sc * ln_g[d] + ln_b[d];
    }
}

// ---------------------------------------------------------------- K7: g = gelu(hs@w1+b1); partial logits per 128-col chunk
__global__ __launch_bounds__(128) void k_mlp(const float* __restrict__ hs, const float* __restrict__ w1,
                                             const float* __restrict__ b1, const float* __restrict__ wh,
                                             float* __restrict__ part_l) {
    const int b = blockIdx.y, tid = threadIdx.x;
    const int j = blockIdx.x * 128 + tid;
    __shared__ float h[DD];
#pragma unroll
    for (int q = 0; q < 6; q++) h[tid + q * 128] = hs[(size_t)b * DD + tid + q * 128];
    __syncthreads();
    float p = b1[j];
#pragma unroll 8
    for (int d = 0; d < DD; d++) p = fmaf(h[d], w1[(size_t)d * DD + j], p);
    const float g = 0.5f * p * (1.0f + erff(p * 0.70710678118654752f));
    float l0 = g * wh[j * 2 + 0];
    float l1 = g * wh[j * 2 + 1];
#pragma unroll
    for (int off = 32; off; off >>= 1) { l0 += __shfl_xor(l0, off); l1 += __shfl_xor(l1, off); }
    __shared__ float r0[2], r1[2];
    if ((tid & 63) == 0) { r0[tid >> 6] = l0; r1[tid >> 6] = l1; }
    __syncthreads();
    if (tid == 0) {
        part_l[((size_t)b * 6 + blockIdx.x) * 2 + 0] = r0[0] + r0[1];
        part_l[((size_t)b * 6 + blockIdx.x) * 2 + 1] = r1[0] + r1[1];
    }
}

// ---------------------------------------------------------------- K8: final logits reduce
__global__ __launch_bounds__(64) void k_final(const float* __restrict__ part_l, const float* __restrict__ bh,
                                              float* __restrict__ out) {
    const int b = threadIdx.x;
    if (b < NB) {
        float l0 = bh[0], l1 = bh[1];
#pragma unroll
        for (int c = 0; c < 6; c++) {
            l0 += part_l[((size_t)b * 6 + c) * 2 + 0];
            l1 += part_l[((size_t)b * 6 + c) * 2 + 1];
        }
        out[b * 2 + 0] = l0;
        out[b * 2 + 1] = l1;
    }
}

// ----------------------------------------------------------------
extern "C" void kernel_launch(void* const* d_in, const int* in_sizes, int n_in,
                              void* d_out, int out_size, void* d_ws, size_t ws_size,
                              hipStream_t stream) {
    const int*   tokens = (const int*)d_in[0];
    const int*   mask   = (const int*)d_in[1];
    const float* emb    = (const float*)d_in[2];
    const float* wq     = (const float*)d_in[3];
    const float* wk     = (const float*)d_in[4];
    const float* wv     = (const float*)d_in[5];
    const float* ln_g   = (const float*)d_in[6];
    const float* ln_b   = (const float*)d_in[7];
    const float* w1     = (const float*)d_in[8];
    const float* b1     = (const float*)d_in[9];
    const float* wh     = (const float*)d_in[10];
    const float* bh     = (const float*)d_in[11];
    float* out = (float*)d_out;

    char* ws = (char*)d_ws;
    const size_t XB = (size_t)NB * SS * DD * 2;   // 50,331,648 B
    const size_t WB = (size_t)DD * DD * 2;        // 1,179,648 B
    ushort* xb  = (ushort*)ws;                    // x bf16
    ushort* yb  = (ushort*)(ws + XB);             // y = x @ W bf16
    ushort* wqb = (ushort*)(ws + 2 * XB);         // wq bf16
    ushort* wkb = (ushort*)(ws + 2 * XB + WB);    // wk bf16
    ushort* Wt  = (ushort*)(ws + 2 * XB + 2 * WB);// Wt[e][d] = (wq wk^T)[d][e] bf16
    char*   p4  = ws + 2 * XB + 3 * WB;
    float*  part   = (float*)p4;                          // 8*32*768*4
    float*  cls    = (float*)(p4 + 786432);               // 32*768*4
    float*  hsb    = (float*)(p4 + 786432 + 98304);       // 32*768*4
    float*  part_l = (float*)(p4 + 786432 + 2 * 98304);   // 32*6*2*4

    float* a_region = out + 64;  // a: B*S*S floats

    k_cvt<<<dim3(576, 2), 256, 0, stream>>>(wq, wk, wqb, wkb);
    k_gather<<<24576, 256, 0, stream>>>(tokens, emb, xb);
    // Wt = wk @ wq^T  (Wt[e][d] = sum_j wk[e,j] wq[d,j] = W[d,e])
    k_gemm_s<<<dim3(6, 6), 256, 0, stream>>>(wkb, wqb, Wt);
    // y = x @ W  (y[s,e] = sum_d x[s,d] Wt[e,d])
    k_gemm_s<<<dim3(256, 6), 256, 0, stream>>>(xb, Wt, yb);
    // a = softmax(y @ x^T + mask), fused, wave-private pipeline
    k_attn<<<512, 512, 0, stream>>>(yb, xb, mask, a_region);
    k_xbar<<<256, 256, 0, stream>>>(a_region, tokens, emb, part);
    k_cls<<<dim3(6, NB), 128, 0, stream>>>(part, wv, cls);
    k_ln<<<NB, 256, 0, stream>>>(cls, ln_g, ln_b, hsb);
    k_mlp<<<dim3(6, NB), 128, 0, stream>>>(hsb, w1, b1, wh, part_l);
    k_final<<<1, 64, 0, stream>>>(part_l, bh, out);
}